// Round 1
// baseline (37226.407 us; speedup 1.0000x reference)
//
#include <hip/hip_runtime.h>
#include <math.h>

#define NT    365
#define NGRID 3000
#define NX    20
#define H     256
#define CPB   12            // cells per block
#define NBLK  (NGRID/CPB)   // 250 blocks
#define KTOT  (2*H)         // 512 (x0 then h)

// workspace layout (floats)
#define WQ_OFF   0
#define WQ_SZ    (KTOT*4*H)        // [512][1024]
#define WINT_OFF (WQ_OFF + WQ_SZ)
#define WINT_SZ  ((NX+1)*H)        // [21][256]
#define BQ_OFF   (WINT_OFF + WINT_SZ)
#define BQ_SZ    (H*4)             // [256][4] = b_ih+b_hh packed per thread

__global__ void prep_kernel(const float* __restrict__ w_in,
                            const float* __restrict__ w_ih,
                            const float* __restrict__ w_hh,
                            const float* __restrict__ b_ih,
                            const float* __restrict__ b_hh,
                            float* __restrict__ ws) {
    int idx = blockIdx.x * blockDim.x + threadIdx.x;
    // Wq[k][jh*4+q] = (k<H ? w_ih : w_hh)[(q*H+jh)][k or k-H]
    if (idx < KTOT * 4 * H) {
        int k   = idx >> 10;
        int col = idx & 1023;
        int jh  = col >> 2;
        int q   = col & 3;
        int j   = q * H + jh;
        float v = (k < H) ? w_ih[j * H + k] : w_hh[j * H + (k - H)];
        ws[WQ_OFF + idx] = v;
    }
    // winT[k][jh] = w_in[jh][k]
    if (idx < (NX + 1) * H) {
        int k  = idx >> 8;
        int jh = idx & 255;
        ws[WINT_OFF + k * H + jh] = w_in[jh * (NX + 1) + k];
    }
    // bq[jh][q] = b_ih[q*H+jh] + b_hh[q*H+jh]
    if (idx < H * 4) {
        int jh = idx >> 2;
        int q  = idx & 3;
        ws[BQ_OFF + jh * 4 + q] = b_ih[q * H + jh] + b_hh[q * H + jh];
    }
}

__device__ __forceinline__ float sigm(float x) { return 1.0f / (1.0f + __expf(-x)); }
__device__ __forceinline__ float tanh_f(float x) { return 2.0f * sigm(2.0f * x) - 1.0f; }

__global__ __launch_bounds__(256, 1)
void lstm_main(const float* __restrict__ x,
               const float* __restrict__ y,
               const float* __restrict__ b_in,
               const float* __restrict__ w_out,
               const float* __restrict__ b_out,
               const float* __restrict__ ws,
               float* __restrict__ out) {
    __shared__ __align__(16) float a_sh[KTOT][16];   // [k][cell], 12 used, pad 16
    __shared__ float xt_sh[CPB][NX];
    __shared__ float yt_sh[CPB];
    __shared__ float red_sh[4][CPB];

    const int tid = threadIdx.x;          // hidden index jh
    const int g0  = blockIdx.x * CPB;

    const float* __restrict__ Wq   = ws + WQ_OFF;
    const float* __restrict__ winT = ws + WINT_OFF;
    const float4 bq     = ((const float4*)(ws + BQ_OFF))[tid];
    const float  b_in_t = b_in[tid];
    const float  wout_t = w_out[tid];
    const float  bout   = b_out[0];

    float c_st[CPB];
    #pragma unroll
    for (int cc = 0; cc < CPB; ++cc) c_st[cc] = 0.0f;
    #pragma unroll
    for (int cc = 0; cc < CPB; ++cc) a_sh[H + tid][cc] = 0.0f;   // h = 0
    if (tid < CPB) yt_sh[tid] = 0.0f;
    __syncthreads();

    for (int t = 0; t < NT; ++t) {
        // ---- P1: stage x[t] tile; fill yt with observations where present
        {
            const float* xt = x + ((size_t)t * NGRID + g0) * NX;
            if (tid < CPB * NX) ((float*)xt_sh)[tid] = xt[tid];
            if (tid < CPB) {
                float yo = y[(size_t)t * NGRID + g0 + tid];
                if (!__builtin_isnan(yo)) yt_sh[tid] = yo;
            }
        }
        __syncthreads();

        // ---- P2: x0 = relu(xcat @ w_in.T + b_in), write into a_sh[0..255]
        {
            float x0v[CPB];
            #pragma unroll
            for (int cc = 0; cc < CPB; ++cc) x0v[cc] = b_in_t;
            #pragma unroll
            for (int k = 0; k < NX; ++k) {
                float w = winT[k * H + tid];
                #pragma unroll
                for (int cc = 0; cc < CPB; ++cc)
                    x0v[cc] = fmaf(xt_sh[cc][k], w, x0v[cc]);
            }
            {
                float w = winT[NX * H + tid];
                #pragma unroll
                for (int cc = 0; cc < CPB; ++cc)
                    x0v[cc] = fmaf(yt_sh[cc], w, x0v[cc]);
            }
            #pragma unroll
            for (int cc = 0; cc < CPB; ++cc)
                a_sh[tid][cc] = fmaxf(x0v[cc], 0.0f);
        }
        __syncthreads();

        // ---- P3: gates GEMM. Thread tid computes gates j = q*256+tid, q=0..3
        float acc0[CPB], acc1[CPB], acc2[CPB], acc3[CPB];
        #pragma unroll
        for (int cc = 0; cc < CPB; ++cc) {
            acc0[cc] = bq.x; acc1[cc] = bq.y; acc2[cc] = bq.z; acc3[cc] = bq.w;
        }
        {
            const float4* __restrict__ wp = ((const float4*)Wq) + tid;
            #pragma unroll 4
            for (int k = 0; k < KTOT; ++k) {
                float4 w = wp[(size_t)k * H];            // Wq row k, this thread's 4 gates
                const float4* arow = (const float4*)(&a_sh[k][0]);
                float4 av0 = arow[0], av1 = arow[1], av2 = arow[2];
                float av[CPB] = { av0.x, av0.y, av0.z, av0.w,
                                  av1.x, av1.y, av1.z, av1.w,
                                  av2.x, av2.y, av2.z, av2.w };
                #pragma unroll
                for (int cc = 0; cc < CPB; ++cc) {
                    acc0[cc] = fmaf(av[cc], w.x, acc0[cc]);
                    acc1[cc] = fmaf(av[cc], w.y, acc1[cc]);
                    acc2[cc] = fmaf(av[cc], w.z, acc2[cc]);
                    acc3[cc] = fmaf(av[cc], w.w, acc3[cc]);
                }
            }
        }
        __syncthreads();   // all reads of a_sh done before h overwrite

        // ---- P4: LSTM pointwise update + h store + y partial reduction
        {
            float hv[CPB];
            #pragma unroll
            for (int cc = 0; cc < CPB; ++cc) {
                float ig = sigm(acc0[cc]);
                float fg = sigm(acc1[cc]);
                float gg = tanh_f(acc2[cc]);
                float og = sigm(acc3[cc]);
                float c  = fmaf(fg, c_st[cc], ig * gg);
                c_st[cc] = c;
                float h  = og * tanh_f(c);
                hv[cc]   = h;
                a_sh[H + tid][cc] = h;
            }
            int wave = tid >> 6;
            #pragma unroll
            for (int cc = 0; cc < CPB; ++cc) {
                float p = hv[cc] * wout_t;
                p += __shfl_xor(p, 32);
                p += __shfl_xor(p, 16);
                p += __shfl_xor(p, 8);
                p += __shfl_xor(p, 4);
                p += __shfl_xor(p, 2);
                p += __shfl_xor(p, 1);
                if ((tid & 63) == 0) red_sh[wave][cc] = p;
            }
        }
        __syncthreads();

        // ---- P5: finalize y, write output, carry prediction as next yt
        if (tid < CPB) {
            float yp = bout + red_sh[0][tid] + red_sh[1][tid]
                            + red_sh[2][tid] + red_sh[3][tid];
            out[(size_t)t * NGRID + g0 + tid] = yp;
            yt_sh[tid] = yp;    // next P1 overwrites with obs where present
        }
        // next iteration's post-P1 barrier makes yt_sh/h visible to all
    }
}

extern "C" void kernel_launch(void* const* d_in, const int* in_sizes, int n_in,
                              void* d_out, int out_size, void* d_ws, size_t ws_size,
                              hipStream_t stream) {
    const float* x     = (const float*)d_in[0];
    const float* y     = (const float*)d_in[1];
    const float* w_in  = (const float*)d_in[2];
    const float* b_in  = (const float*)d_in[3];
    const float* w_ih  = (const float*)d_in[4];
    const float* b_ih  = (const float*)d_in[5];
    const float* w_hh  = (const float*)d_in[6];
    const float* b_hh  = (const float*)d_in[7];
    const float* w_out = (const float*)d_in[8];
    const float* b_out = (const float*)d_in[9];
    float* ws  = (float*)d_ws;
    float* out = (float*)d_out;

    prep_kernel<<<(KTOT * 4 * H + 255) / 256, 256, 0, stream>>>(
        w_in, w_ih, w_hh, b_ih, b_hh, ws);
    lstm_main<<<NBLK, 256, 0, stream>>>(x, y, b_in, w_out, b_out, ws, out);
}

// Round 2
// 8492.086 us; speedup vs baseline: 4.3837x; 4.3837x over previous
//
#include <hip/hip_runtime.h>
#include <math.h>

#define NT     365
#define NGRID  3000
#define NX     20
#define H      256
#define CPB    30
#define NBLK   (NGRID/CPB)     // 100
#define THREADS 512
#define MT     2               // m-tiles (32 rows, 30 used)

// packed weight sizes (ushorts)
#define WPK_US   (16*16*8*64*8)   // 1,048,576  (g,kap,c,lane,e)
#define WPKIN_US (16*2*64*8)      // 16,384     (tau,d,lane,e)

typedef short v8s __attribute__((ext_vector_type(8)));
typedef float v4f __attribute__((ext_vector_type(4)));
#define MFMA_BF16 __builtin_amdgcn_mfma_f32_16x16x32_bf16

__device__ __forceinline__ unsigned short f2bf(float f) {
    unsigned int u = __float_as_uint(f);
    u += 0x7fffu + ((u >> 16) & 1u);          // RTNE
    return (unsigned short)(u >> 16);
}
__device__ __forceinline__ float bf2f(unsigned short h) {
    return __uint_as_float(((unsigned int)h) << 16);
}
__device__ __forceinline__ float sigm(float x)  { return 1.0f / (1.0f + __expf(-x)); }
__device__ __forceinline__ float tanh_f(float x){ return 2.0f * sigm(2.0f * x) - 1.0f; }

// ---------------- weight pre-pack ----------------
// wpk: B-fragment order for gates GEMM. chunk(g,kap,c): c = q*2+d (d: 0=hi,1=lo)
//   lane holds W[k = kap*32 + (lane>>4)*8 + e][j = q*256 + g*16 + (lane&15)]
//   W[k][j] = k<256 ? w_ih[j][k] : w_hh[j][k-256]
// wpkin: same for w_in^T (K padded 21->32 with zeros), tiles tau 0..15, kap=0.
__global__ void prep_kernel(const float* __restrict__ w_in,
                            const float* __restrict__ w_ih,
                            const float* __restrict__ w_hh,
                            const float* __restrict__ b_ih,
                            const float* __restrict__ b_hh,
                            unsigned short* __restrict__ wpk,
                            unsigned short* __restrict__ wpkin,
                            float* __restrict__ bsum) {
    int idx = blockIdx.x * 256 + threadIdx.x;
    if (idx < WPK_US) {
        int e    = idx & 7;
        int lane = (idx >> 3) & 63;
        int c    = (idx >> 9) & 7;
        int gk   = idx >> 12;            // 0..255
        int kap  = gk & 15, g = gk >> 4;
        int q = c >> 1, d = c & 1;
        int k = kap * 32 + ((lane >> 4) << 3) + e;
        int j = q * 256 + g * 16 + (lane & 15);
        float wv = (k < 256) ? w_ih[j * 256 + k] : w_hh[j * 256 + (k - 256)];
        unsigned short hi = f2bf(wv);
        wpk[idx] = d ? f2bf(wv - bf2f(hi)) : hi;
    }
    if (idx < WPKIN_US) {
        int e    = idx & 7;
        int lane = (idx >> 3) & 63;
        int d    = (idx >> 9) & 1;
        int tau  = idx >> 10;            // 0..15
        int k = ((lane >> 4) << 3) + e;
        int n = tau * 16 + (lane & 15);
        float wv = (k < NX + 1) ? w_in[n * (NX + 1) + k] : 0.0f;
        unsigned short hi = f2bf(wv);
        wpkin[idx] = d ? f2bf(wv - bf2f(hi)) : hi;
    }
    if (idx < 4 * H) bsum[idx] = b_ih[idx] + b_hh[idx];
}

// ---------------- main persistent LSTM ----------------
__global__ __launch_bounds__(THREADS, 2)
void lstm_main(const float* __restrict__ x,
               const float* __restrict__ y,
               const float* __restrict__ b_in,
               const float* __restrict__ w_out,
               const float* __restrict__ b_out,
               const unsigned short* __restrict__ wpk,
               const unsigned short* __restrict__ wpkin,
               const float* __restrict__ bsum,
               float* __restrict__ out) {
    // fragment-major activation buffers: [mt][kap][lane*8+e], lane = qp*16 + m
    __shared__ __align__(16) unsigned short Agh[MT][16][512];
    __shared__ __align__(16) unsigned short Agl[MT][16][512];
    __shared__ __align__(16) unsigned short Xh[MT][512];
    __shared__ __align__(16) unsigned short Xl[MT][512];
    __shared__ float y_part[8][32];

    const int tid  = threadIdx.x;
    const int w    = tid >> 6;          // wave 0..7
    const int lane = tid & 63;
    const int col  = lane & 15;
    const int quad = lane >> 4;
    const int g0   = blockIdx.x * CPB;

    // zero-init LDS (h region must be 0 at t=0; xcat pad cols stay 0 forever)
    {
        unsigned int* p;
        p = (unsigned int*)&Agh[0][0][0];
        for (int i = tid; i < MT * 16 * 256; i += THREADS) p[i] = 0u;
        p = (unsigned int*)&Agl[0][0][0];
        for (int i = tid; i < MT * 16 * 256; i += THREADS) p[i] = 0u;
        p = (unsigned int*)&Xh[0][0];
        for (int i = tid; i < MT * 256; i += THREADS) p[i] = 0u;
        p = (unsigned int*)&Xl[0][0];
        for (int i = tid; i < MT * 256; i += THREADS) p[i] = 0u;
    }
    float c_st[2][MT][4];
    #pragma unroll
    for (int a = 0; a < 2; ++a)
        #pragma unroll
        for (int b = 0; b < MT; ++b)
            #pragma unroll
            for (int r = 0; r < 4; ++r) c_st[a][b][r] = 0.0f;
    __syncthreads();

    for (int t = 0; t < NT; ++t) {
        // ---- P1: stage x[t] (bf16 hi/lo, frag-major) + observed y fill
        {
            const float* xr = x + ((size_t)t * NGRID + g0) * NX;
            for (int i = tid; i < CPB * NX; i += THREADS) {
                float v  = xr[i];
                int cell = i / NX;
                int k    = i - cell * NX;
                int mt   = cell >> 4, m = cell & 15;
                int pos  = (((k >> 3) << 4) + m) * 8 + (k & 7);
                unsigned short hi = f2bf(v);
                Xh[mt][pos] = hi;
                Xl[mt][pos] = f2bf(v - bf2f(hi));
            }
            if (tid < CPB) {
                float yo = y[(size_t)t * NGRID + g0 + tid];
                if (!__builtin_isnan(yo)) {
                    int mt = tid >> 4, m = tid & 15;
                    int pos = (2 * 16 + m) * 8 + 4;       // k = 20
                    unsigned short hi = f2bf(yo);
                    Xh[mt][pos] = hi;
                    Xl[mt][pos] = f2bf(yo - bf2f(hi));
                }
            }
        }
        __syncthreads();

        // ---- X: x0 = relu(xcat @ w_in^T + b_in) via MFMA, write into A k=0..255
        {
            #pragma unroll
            for (int i = 0; i < 4; ++i) {
                int tileid = w * 4 + i;
                int tau = tileid >> 1, mt = tileid & 1;
                v8s xah = *(const v8s*)&Xh[mt][lane * 8];
                v8s xal = *(const v8s*)&Xl[mt][lane * 8];
                v8s bh  = *(const v8s*)(wpkin + (tau * 2 + 0) * 512 + lane * 8);
                v8s bl  = *(const v8s*)(wpkin + (tau * 2 + 1) * 512 + lane * 8);
                v4f acc = {0.0f, 0.0f, 0.0f, 0.0f};
                acc = MFMA_BF16(xah, bh, acc, 0, 0, 0);
                acc = MFMA_BF16(xah, bl, acc, 0, 0, 0);
                acc = MFMA_BF16(xal, bh, acc, 0, 0, 0);
                int jh = tau * 16 + col;
                float bi = b_in[jh];
                int kq = jh >> 5, qp = (jh >> 3) & 3, e = jh & 7;
                #pragma unroll
                for (int r = 0; r < 4; ++r) {
                    int cellm = quad * 4 + r;
                    int cell  = mt * 16 + cellm;
                    if (cell < CPB) {
                        float v = fmaxf(acc[r] + bi, 0.0f);
                        unsigned short hi = f2bf(v);
                        int pos = (qp * 16 + cellm) * 8 + e;
                        Agh[mt][kq][pos] = hi;
                        Agl[mt][kq][pos] = f2bf(v - bf2f(hi));
                    }
                }
            }
        }
        __syncthreads();

        // ---- G: gates GEMM. wave handles quad-groups g = 2w, 2w+1.
        v4f acc[2][MT][4];
        #pragma unroll
        for (int qg = 0; qg < 2; ++qg)
            #pragma unroll
            for (int mt = 0; mt < MT; ++mt)
                #pragma unroll
                for (int q = 0; q < 4; ++q) acc[qg][mt][q] = (v4f){0, 0, 0, 0};

        #pragma unroll 4
        for (int kap = 0; kap < 16; ++kap) {
            v8s Ah[MT], Al[MT];
            #pragma unroll
            for (int mt = 0; mt < MT; ++mt) {
                Ah[mt] = *(const v8s*)&Agh[mt][kap][lane * 8];
                Al[mt] = *(const v8s*)&Agl[mt][kap][lane * 8];
            }
            #pragma unroll
            for (int qg = 0; qg < 2; ++qg) {
                const unsigned short* bp =
                    wpk + (size_t)(((2 * w + qg) * 16 + kap) * 8) * 512 + lane * 8;
                v8s B[8];
                #pragma unroll
                for (int c = 0; c < 8; ++c)
                    B[c] = *(const v8s*)(bp + c * 512);
                #pragma unroll
                for (int mt = 0; mt < MT; ++mt) {
                    #pragma unroll
                    for (int q = 0; q < 4; ++q) {
                        acc[qg][mt][q] = MFMA_BF16(Ah[mt], B[2 * q],     acc[qg][mt][q], 0, 0, 0);
                        acc[qg][mt][q] = MFMA_BF16(Ah[mt], B[2 * q + 1], acc[qg][mt][q], 0, 0, 0);
                        acc[qg][mt][q] = MFMA_BF16(Al[mt], B[2 * q],     acc[qg][mt][q], 0, 0, 0);
                    }
                }
            }
        }
        __syncthreads();   // all A reads done -> safe to overwrite h region

        // ---- E: pointwise LSTM + h writeback + y partial
        {
            float yp[MT][4];
            #pragma unroll
            for (int mt = 0; mt < MT; ++mt)
                #pragma unroll
                for (int r = 0; r < 4; ++r) yp[mt][r] = 0.0f;

            #pragma unroll
            for (int qg = 0; qg < 2; ++qg) {
                int g  = 2 * w + qg;
                int jh = g * 16 + col;
                float b_i = bsum[jh];
                float b_f = bsum[256 + jh];
                float b_g = bsum[512 + jh];
                float b_o = bsum[768 + jh];
                float wo  = w_out[jh];
                int kq = 8 + (g >> 1);
                int qp = (jh >> 3) & 3, e = jh & 7;
                #pragma unroll
                for (int mt = 0; mt < MT; ++mt) {
                    #pragma unroll
                    for (int r = 0; r < 4; ++r) {
                        int cellm = quad * 4 + r;
                        int cell  = mt * 16 + cellm;
                        float iv = acc[qg][mt][0][r] + b_i;
                        float fv = acc[qg][mt][1][r] + b_f;
                        float gv = acc[qg][mt][2][r] + b_g;
                        float ov = acc[qg][mt][3][r] + b_o;
                        float c  = fmaf(sigm(fv), c_st[qg][mt][r], sigm(iv) * tanh_f(gv));
                        c_st[qg][mt][r] = c;
                        float h  = sigm(ov) * tanh_f(c);
                        if (cell < CPB) {
                            unsigned short hi = f2bf(h);
                            int pos = (qp * 16 + cellm) * 8 + e;
                            Agh[mt][kq][pos] = hi;
                            Agl[mt][kq][pos] = f2bf(h - bf2f(hi));
                            yp[mt][r] += h * wo;
                        }
                    }
                }
            }
            // reduce over the 16 cols (low 4 lane bits)
            #pragma unroll
            for (int mt = 0; mt < MT; ++mt)
                #pragma unroll
                for (int r = 0; r < 4; ++r) {
                    float p = yp[mt][r];
                    p += __shfl_xor(p, 1);
                    p += __shfl_xor(p, 2);
                    p += __shfl_xor(p, 4);
                    p += __shfl_xor(p, 8);
                    yp[mt][r] = p;
                }
            if (col == 0) {
                #pragma unroll
                for (int mt = 0; mt < MT; ++mt)
                    #pragma unroll
                    for (int r = 0; r < 4; ++r)
                        y_part[w][mt * 16 + quad * 4 + r] = yp[mt][r];
            }
        }
        __syncthreads();

        // ---- P5: finalize y, store, feed back into xcat k=20
        if (tid < CPB) {
            float yv = b_out[0];
            #pragma unroll
            for (int w2 = 0; w2 < 8; ++w2) yv += y_part[w2][tid];
            out[(size_t)t * NGRID + g0 + tid] = yv;
            int mt = tid >> 4, m = tid & 15;
            int pos = (2 * 16 + m) * 8 + 4;               // k = 20
            unsigned short hi = f2bf(yv);
            Xh[mt][pos] = hi;
            Xl[mt][pos] = f2bf(yv - bf2f(hi));
        }
        __syncthreads();
    }
}

extern "C" void kernel_launch(void* const* d_in, const int* in_sizes, int n_in,
                              void* d_out, int out_size, void* d_ws, size_t ws_size,
                              hipStream_t stream) {
    const float* x     = (const float*)d_in[0];
    const float* y     = (const float*)d_in[1];
    const float* w_in  = (const float*)d_in[2];
    const float* b_in  = (const float*)d_in[3];
    const float* w_ih  = (const float*)d_in[4];
    const float* b_ih  = (const float*)d_in[5];
    const float* w_hh  = (const float*)d_in[6];
    const float* b_hh  = (const float*)d_in[7];
    const float* w_out = (const float*)d_in[8];
    const float* b_out = (const float*)d_in[9];

    unsigned short* wpk   = (unsigned short*)d_ws;
    unsigned short* wpkin = wpk + WPK_US;
    float*          bsum  = (float*)(wpkin + WPKIN_US);
    float*          out   = (float*)d_out;

    prep_kernel<<<(WPK_US + 255) / 256, 256, 0, stream>>>(
        w_in, w_ih, w_hh, b_ih, b_hh, wpk, wpkin, bsum);
    lstm_main<<<NBLK, THREADS, 0, stream>>>(
        x, y, b_in, w_out, b_out, wpk, wpkin, bsum, out);
}